// Round 9
// baseline (463.156 us; speedup 1.0000x reference)
//
#include <hip/hip_runtime.h>
#include <math.h>

#define NB 256
#define NT 128
#define NDW 300
#define NH 128
#define NTYPE 8
#define NLEVEL 13
#define NN (NB*NT)

#define NBK 104       // (height 0..12) x (type 0..7) node buckets
#define CBLOCKS 64
#define PBLOCKS 1024  // phase grid: 128 subs per type x 8 types

// ib layout (ints), at byte offset 16MB of d_ws
#define BC 0                    // [CBLOCKS][NBK] per-block counts
#define BB 8192                 // [CBLOCKS][NBK] per-block base offsets
#define OFF 16384               // [NBK+1] bucket starts
#define NODE_LIST 16512         // [NN]

typedef __attribute__((ext_vector_type(8))) short short8;
typedef __attribute__((ext_vector_type(4))) float f32x4;

__global__ __launch_bounds__(256) void count_kernel(const int* __restrict__ dep_type,
    const int* __restrict__ height, int* ib) {
  __shared__ int cnt[NBK];
  for (int u = threadIdx.x; u < NBK; u += 256) cnt[u] = 0;
  __syncthreads();
  for (int i = blockIdx.x*256 + threadIdx.x; i < NN; i += CBLOCKS*256)
    atomicAdd(&cnt[height[i]*NTYPE + dep_type[i]], 1);
  __syncthreads();
  for (int u = threadIdx.x; u < NBK; u += 256)
    ib[BC + blockIdx.x*NBK + u] = cnt[u];
}

__global__ __launch_bounds__(128) void scan_kernel(int* ib) {
  __shared__ int total[NBK], start[NBK];
  int u = threadIdx.x;
  if (u < NBK) {
    int acc = 0;
    for (int b = 0; b < CBLOCKS; b++) {
      ib[BB + b*NBK + u] = acc;
      acc += ib[BC + b*NBK + u];
    }
    total[u] = acc;
  }
  __syncthreads();
  if (u == 0) {
    int acc = 0;
    for (int e = 0; e < NBK; e++) { start[e] = acc; ib[OFF+e] = acc; acc += total[e]; }
    ib[OFF+NBK] = acc;
  }
  __syncthreads();
  if (u < NBK) {
    int s = start[u];
    for (int b = 0; b < CBLOCKS; b++) ib[BB + b*NBK + u] += s;
  }
}

__global__ __launch_bounds__(256) void scatter_kernel(const int* __restrict__ dep_type,
    const int* __restrict__ height, int* ib) {
  __shared__ int base[NBK];
  __shared__ int cnt[NBK];
  for (int u = threadIdx.x; u < NBK; u += 256) {
    base[u] = ib[BB + blockIdx.x*NBK + u];
    cnt[u] = 0;
  }
  __syncthreads();
  for (int i = blockIdx.x*256 + threadIdx.x; i < NN; i += CBLOCKS*256) {
    int bk = height[i]*NTYPE + dep_type[i];
    int pos = atomicAdd(&cnt[bk], 1);
    ib[NODE_LIST + base[bk] + pos] = i;
  }
}

__device__ __forceinline__ unsigned int pack_bf16(float a, float b) {
  unsigned int ua = __float_as_uint(a); ua += 0x7fff + ((ua >> 16) & 1);
  unsigned int ub = __float_as_uint(b); ub += 0x7fff + ((ub >> 16) & 1);
  return (ua >> 16) | (ub & 0xffff0000u);
}

// fast tanh: 1 - 2*rcp(e^{2x}+1); exact at +/-inf, ~1e-6 abs error
__device__ __forceinline__ float ftanh(float x) {
  float e = __expf(2.0f * x);
  return 1.0f - 2.0f * __builtin_amdgcn_rcpf(e + 1.0f);
}

// Build transposed-packed bf16 weights: bwT[mat][d4][row] = uint2 of
// 4 bf16 = W[mat][row][4*d4 .. 4*d4+3].  mat 0 = W_hr, mat 1+t = W_rel[t].
// One thread per uint2: flat = mat*4096 + d4*128 + row  (writes coalesced).
__global__ __launch_bounds__(256) void wcvt_kernel(const float* __restrict__ Whr,
    const float* __restrict__ Wrel, uint2* __restrict__ bwT) {
  int flat = blockIdx.x*256 + threadIdx.x;     // 0 .. 9*4096-1
  int mat = flat >> 12, rem = flat & 4095;
  int d4 = rem >> 7, row = rem & 127;
  const float* src = (mat == 0) ? &Whr[row*NH + d4*4]
                                : &Wrel[(size_t)(mat-1)*NH*NH + row*NH + d4*4];
  float4 v = *(const float4*)src;
  uint2 u; u.x = pack_bf16(v.x, v.y); u.y = pack_bf16(v.z, v.w);
  bwT[flat] = u;
}

// wx = token_emb @ W_wh.T via MFMA bf16. Tile 64m x 128n, K chunks of 32 (300 pad 320).
__global__ __launch_bounds__(256) void wx_kernel(const float* __restrict__ x,
    const float* __restrict__ Wwh, float* __restrict__ wx, float* __restrict__ hbuf) {
  __shared__ __align__(16) unsigned int sA[64*16];    // [row][16 uints] = 32 bf16/row
  __shared__ __align__(16) unsigned int sB[128*16];
  int tid = threadIdx.x;
  int wave = tid >> 6, lane = tid & 63;
  size_t rowbase = (size_t)blockIdx.x * 64;
  f32x4 acc[8];
  #pragma unroll
  for (int ni = 0; ni < 8; ni++) acc[ni] = (f32x4){0.f,0.f,0.f,0.f};
  for (int kc = 0; kc < 320; kc += 32) {
    __syncthreads();
    #pragma unroll
    for (int q = 0; q < 2; q++) {             // stage A: 64 rows x 8 float4
      int flat = tid + q*256; int r = flat >> 3, f4 = flat & 7;
      int k0 = kc + f4*4;
      float4 v = make_float4(0.f,0.f,0.f,0.f);
      if (k0 + 3 < NDW) v = *(const float4*)&x[(rowbase + r)*NDW + k0];
      uint2 u; u.x = pack_bf16(v.x, v.y); u.y = pack_bf16(v.z, v.w);
      *(uint2*)&sA[r*16 + f4*2] = u;
    }
    #pragma unroll
    for (int q = 0; q < 4; q++) {             // stage B: 128 rows x 8 float4
      int flat = tid + q*256; int r = flat >> 3, f4 = flat & 7;
      int k0 = kc + f4*4;
      float4 v = make_float4(0.f,0.f,0.f,0.f);
      if (k0 + 3 < NDW) v = *(const float4*)&Wwh[(size_t)r*NDW + k0];
      uint2 u; u.x = pack_bf16(v.x, v.y); u.y = pack_bf16(v.z, v.w);
      *(uint2*)&sB[r*16 + f4*2] = u;
    }
    __syncthreads();
    short8 a = *(const short8*)&sA[(wave*16 + (lane & 15))*16 + (lane >> 4)*4];
    #pragma unroll
    for (int ni = 0; ni < 8; ni++) {
      short8 b = *(const short8*)&sB[(ni*16 + (lane & 15))*16 + (lane >> 4)*4];
      acc[ni] = __builtin_amdgcn_mfma_f32_16x16x32_bf16(a, b, acc[ni], 0, 0, 0);
    }
  }
  int rbase = wave*16 + (lane >> 4)*4;
  #pragma unroll
  for (int ni = 0; ni < 8; ni++)
    #pragma unroll
    for (int reg = 0; reg < 4; reg++)
      wx[(rowbase + rbase + reg)*NH + ni*16 + (lane & 15)] = acc[ni][reg];
  float4 z = make_float4(0.f,0.f,0.f,0.f);
  #pragma unroll
  for (int q = 0; q < 8; q++) {
    int flat = tid + q*256; int r = flat >> 5, c = flat & 31;
    *(float4*)&hbuf[(rowbase + r)*NH + c*4] = z;
  }
}

// 8-node batched matvec; transposed-packed bf16 weights from global (coalesced:
// lane l loads wt[d4*128 + l] -> consecutive 8B across lanes = 1 transaction).
__device__ __forceinline__ void matvec8_T(const uint2* __restrict__ wt,
    int lane, const float (*sv)[NH], float* o0, float* o1) {
  #pragma unroll
  for (int j = 0; j < 8; j++) { o0[j] = 0.f; o1[j] = 0.f; }
  #pragma unroll 4
  for (int d4 = 0; d4 < 32; d4++) {
    uint2 u0 = wt[d4*128 + lane];        // row = lane
    uint2 u1 = wt[d4*128 + lane + 64];   // row = lane+64
    float w00 = __uint_as_float(u0.x << 16), w01 = __uint_as_float(u0.x & 0xffff0000u);
    float w02 = __uint_as_float(u0.y << 16), w03 = __uint_as_float(u0.y & 0xffff0000u);
    float w10 = __uint_as_float(u1.x << 16), w11 = __uint_as_float(u1.x & 0xffff0000u);
    float w12 = __uint_as_float(u1.y << 16), w13 = __uint_as_float(u1.y & 0xffff0000u);
    #pragma unroll
    for (int j = 0; j < 8; j++) {
      float4 v = *(const float4*)&sv[j][d4*4];    // wave-uniform: LDS broadcast
      o0[j] += w00*v.x + w01*v.y + w02*v.z + w03*v.w;
      o1[j] += w10*v.x + w11*v.y + w12*v.z + w13*v.w;
    }
  }
}

// Phase k: nodes with height==k, bucketed by dep_type t=blockIdx&7:
//   h_i = tanh(hbuf_i + simple_i)  (simple_i at k==0) -> hbuf_i final
//   g_i = W_hr.h_i ; r = tanh(g_i + wx_parent); infl = W_rel[t].r -> atomicAdd hbuf[parent]
// 8 nodes per wave; two-pass gathers; coalesced bf16 weight stream; LDS 16KB.
__global__ __launch_bounds__(256, 4) void phase_kernel(
    const uint2* __restrict__ bwT, const float* __restrict__ bwh,
    const float* __restrict__ wx, const int* __restrict__ parent,
    const int* __restrict__ ib, float* __restrict__ hbuf, int k) {
  int t = blockIdx.x & 7, sub = blockIdx.x >> 3;     // 128 subs per type
  int bs = ib[OFF + k*NTYPE + t];
  int be = ib[OFF + k*NTYPE + t + 1];
  int nbat = (be - bs + 7) >> 3;
  if (sub*4 >= nbat) return;                         // uniform early-exit
  __shared__ __align__(16) float sh[4][8][NH];       // 16 KB
  int wave = threadIdx.x >> 6, lane = threadIdx.x & 63;
  const uint2* whr_t  = bwT;                         // mat 0
  const uint2* wrel_t = bwT + (size_t)(1 + t)*4096;  // mat 1+t
  float b0 = bwh[lane], b1 = bwh[64+lane];
  for (int b = sub*4 + wave; b < nbat; b += 128*4) {
    int base = bs + b*8;
    int cnt = be - base; if (cnt > 8) cnt = 8;
    int idxs[8], pidx[8];
    // pass 1: node indices
    #pragma unroll
    for (int j = 0; j < 8; j++) {
      int it = base + j; if (it >= be) it = be - 1;  // clamp tail (wave-uniform)
      idxs[j] = ib[NODE_LIST + it];
    }
    // pass 2: all row loads issued back-to-back (max loads in flight)
    float wxv0[8], wxv1[8], hb0[8], hb1[8];
    #pragma unroll
    for (int j = 0; j < 8; j++) {
      wxv0[j] = wx[(size_t)idxs[j]*NH + lane];
      wxv1[j] = wx[(size_t)idxs[j]*NH + 64 + lane];
    }
    if (k > 0) {
      #pragma unroll
      for (int j = 0; j < 8; j++) {
        hb0[j] = hbuf[(size_t)idxs[j]*NH + lane];
        hb1[j] = hbuf[(size_t)idxs[j]*NH + 64 + lane];
      }
    }
    #pragma unroll
    for (int j = 0; j < 8; j++) {
      int p = parent[idxs[j]];
      pidx[j] = (j < cnt && p >= 0) ? (idxs[j] & ~(NT-1)) + p : -1;
    }
    // prefetch parent wx rows early: latency hides under matvec1
    float pw0[8], pw1[8];
    #pragma unroll
    for (int j = 0; j < 8; j++) {
      int p = pidx[j] >= 0 ? pidx[j] : idxs[j];
      pw0[j] = wx[(size_t)p*NH + lane];
      pw1[j] = wx[(size_t)p*NH + 64 + lane];
    }
    // finalize h, publish to LDS + hbuf
    #pragma unroll
    for (int j = 0; j < 8; j++) {
      float s0 = ftanh(wxv0[j] + b0);
      float s1 = ftanh(wxv1[j] + b1);
      float h0, h1;
      if (k == 0) { h0 = s0; h1 = s1; }
      else { h0 = ftanh(hb0[j] + s0); h1 = ftanh(hb1[j] + s1); }
      if (j < cnt) {
        hbuf[(size_t)idxs[j]*NH + lane]      = h0;  // final h for node i
        hbuf[(size_t)idxs[j]*NH + 64 + lane] = h1;
      }
      sh[wave][j][lane] = h0; sh[wave][j][64+lane] = h1;   // wave-synchronous LDS
    }
    float g0[8], g1[8];
    matvec8_T(whr_t, lane, sh[wave], g0, g1);        // g = W_hr . h
    #pragma unroll
    for (int j = 0; j < 8; j++) {                    // r = tanh(g + wx_parent)
      float r0 = ftanh(g0[j] + pw0[j]);
      float r1 = ftanh(g1[j] + pw1[j]);
      sh[wave][j][lane] = r0; sh[wave][j][64+lane] = r1;
    }
    float o0[8], o1[8];
    matvec8_T(wrel_t, lane, sh[wave], o0, o1);       // infl = W_rel[t] . r
    #pragma unroll
    for (int j = 0; j < 8; j++) if (pidx[j] >= 0) {
      atomicAdd(&hbuf[(size_t)pidx[j]*NH + lane],      o0[j]);
      atomicAdd(&hbuf[(size_t)pidx[j]*NH + 64 + lane], o1[j]);
    }
  }
}

extern "C" void kernel_launch(void* const* d_in, const int* in_sizes, int n_in,
                              void* d_out, int out_size, void* d_ws, size_t ws_size,
                              hipStream_t stream) {
  const float* token  = (const float*)d_in[0];
  const float* Wwh    = (const float*)d_in[1];
  const float* bwh    = (const float*)d_in[2];
  const float* Whr    = (const float*)d_in[3];
  const float* Wrel   = (const float*)d_in[4];
  const int*   parent = (const int*)d_in[5];
  const int*   dep    = (const int*)d_in[6];
  const int*   height = (const int*)d_in[7];

  float* hbuf = (float*)d_out;                          // seg-accumulator, then final h
  float* wx   = (float*)d_ws;                           // [NN,NH] f32, 16MB
  int*   ib   = (int*)((char*)d_ws + 16777216);         // bucket metadata + node list
  uint2* bwT  = (uint2*)((char*)d_ws + 16777216 + 1048576);  // 9*32KB bf16 weights

  wcvt_kernel<<<144, 256, 0, stream>>>(Whr, Wrel, bwT);
  count_kernel<<<CBLOCKS, 256, 0, stream>>>(dep, height, ib);
  scan_kernel<<<1, 128, 0, stream>>>(ib);
  scatter_kernel<<<CBLOCKS, 256, 0, stream>>>(dep, height, ib);
  wx_kernel<<<NN/64, 256, 0, stream>>>(token, Wwh, wx, hbuf);
  for (int k = 0; k < NLEVEL; k++)
    phase_kernel<<<PBLOCKS, 256, 0, stream>>>(bwT, bwh, wx, parent, ib, hbuf, k);
}

// Round 10
// 337.843 us; speedup vs baseline: 1.3709x; 1.3709x over previous
//
#include <hip/hip_runtime.h>
#include <math.h>

#define NB 256
#define NT 128
#define NDW 300
#define NH 128
#define NTYPE 8
#define NLEVEL 13
#define NN (NB*NT)

#define NBK 104       // (height 0..12) x (type 0..7) node buckets
#define CBLOCKS 64
#define PBLOCKS 1024  // phase grid: 128 subs per type x 8 types

// ib layout (ints), at byte offset 16MB of d_ws
#define BC 0                    // [CBLOCKS][NBK] per-block counts
#define BB 8192                 // [CBLOCKS][NBK] per-block base offsets
#define OFF 16384               // [NBK+1] bucket starts
#define NODE_LIST 16512         // [NN]

typedef __attribute__((ext_vector_type(8))) short short8;
typedef __attribute__((ext_vector_type(4))) float f32x4;

__global__ __launch_bounds__(256) void count_kernel(const int* __restrict__ dep_type,
    const int* __restrict__ height, int* ib) {
  __shared__ int cnt[NBK];
  for (int u = threadIdx.x; u < NBK; u += 256) cnt[u] = 0;
  __syncthreads();
  for (int i = blockIdx.x*256 + threadIdx.x; i < NN; i += CBLOCKS*256)
    atomicAdd(&cnt[height[i]*NTYPE + dep_type[i]], 1);
  __syncthreads();
  for (int u = threadIdx.x; u < NBK; u += 256)
    ib[BC + blockIdx.x*NBK + u] = cnt[u];
}

__global__ __launch_bounds__(128) void scan_kernel(int* ib) {
  __shared__ int total[NBK], start[NBK];
  int u = threadIdx.x;
  if (u < NBK) {
    int acc = 0;
    for (int b = 0; b < CBLOCKS; b++) {
      ib[BB + b*NBK + u] = acc;
      acc += ib[BC + b*NBK + u];
    }
    total[u] = acc;
  }
  __syncthreads();
  if (u == 0) {
    int acc = 0;
    for (int e = 0; e < NBK; e++) { start[e] = acc; ib[OFF+e] = acc; acc += total[e]; }
    ib[OFF+NBK] = acc;
  }
  __syncthreads();
  if (u < NBK) {
    int s = start[u];
    for (int b = 0; b < CBLOCKS; b++) ib[BB + b*NBK + u] += s;
  }
}

__global__ __launch_bounds__(256) void scatter_kernel(const int* __restrict__ dep_type,
    const int* __restrict__ height, int* ib) {
  __shared__ int base[NBK];
  __shared__ int cnt[NBK];
  for (int u = threadIdx.x; u < NBK; u += 256) {
    base[u] = ib[BB + blockIdx.x*NBK + u];
    cnt[u] = 0;
  }
  __syncthreads();
  for (int i = blockIdx.x*256 + threadIdx.x; i < NN; i += CBLOCKS*256) {
    int bk = height[i]*NTYPE + dep_type[i];
    int pos = atomicAdd(&cnt[bk], 1);
    ib[NODE_LIST + base[bk] + pos] = i;
  }
}

__device__ __forceinline__ unsigned int pack_bf16(float a, float b) {
  unsigned int ua = __float_as_uint(a); ua += 0x7fff + ((ua >> 16) & 1);
  unsigned int ub = __float_as_uint(b); ub += 0x7fff + ((ub >> 16) & 1);
  return (ua >> 16) | (ub & 0xffff0000u);
}

// fast tanh: 1 - 2*rcp(e^{2x}+1); exact at +/-inf, ~1e-6 abs error
__device__ __forceinline__ float ftanh(float x) {
  float e = __expf(2.0f * x);
  return 1.0f - 2.0f * __builtin_amdgcn_rcpf(e + 1.0f);
}

// Transposed-packed bf16 weights: bwT[mat][d4][row] = uint2 of 4 bf16 =
// W[mat][row][4*d4..4*d4+3]. mat 0 = W_hr, mat 1+t = W_rel[t]. Coalesced build.
__global__ __launch_bounds__(256) void wcvt_kernel(const float* __restrict__ Whr,
    const float* __restrict__ Wrel, uint2* __restrict__ bwT) {
  int flat = blockIdx.x*256 + threadIdx.x;     // 0 .. 9*4096-1
  int mat = flat >> 12, rem = flat & 4095;
  int d4 = rem >> 7, row = rem & 127;
  const float* src = (mat == 0) ? &Whr[row*NH + d4*4]
                                : &Wrel[(size_t)(mat-1)*NH*NH + row*NH + d4*4];
  float4 v = *(const float4*)src;
  uint2 u; u.x = pack_bf16(v.x, v.y); u.y = pack_bf16(v.z, v.w);
  bwT[flat] = u;
}

// wx = token_emb @ W_wh.T via MFMA bf16. Tile 64m x 128n, K chunks of 32 (300 pad 320).
__global__ __launch_bounds__(256) void wx_kernel(const float* __restrict__ x,
    const float* __restrict__ Wwh, float* __restrict__ wx, float* __restrict__ hbuf) {
  __shared__ __align__(16) unsigned int sA[64*16];    // [row][16 uints] = 32 bf16/row
  __shared__ __align__(16) unsigned int sB[128*16];
  int tid = threadIdx.x;
  int wave = tid >> 6, lane = tid & 63;
  size_t rowbase = (size_t)blockIdx.x * 64;
  f32x4 acc[8];
  #pragma unroll
  for (int ni = 0; ni < 8; ni++) acc[ni] = (f32x4){0.f,0.f,0.f,0.f};
  for (int kc = 0; kc < 320; kc += 32) {
    __syncthreads();
    #pragma unroll
    for (int q = 0; q < 2; q++) {             // stage A: 64 rows x 8 float4
      int flat = tid + q*256; int r = flat >> 3, f4 = flat & 7;
      int k0 = kc + f4*4;
      float4 v = make_float4(0.f,0.f,0.f,0.f);
      if (k0 + 3 < NDW) v = *(const float4*)&x[(rowbase + r)*NDW + k0];
      uint2 u; u.x = pack_bf16(v.x, v.y); u.y = pack_bf16(v.z, v.w);
      *(uint2*)&sA[r*16 + f4*2] = u;
    }
    #pragma unroll
    for (int q = 0; q < 4; q++) {             // stage B: 128 rows x 8 float4
      int flat = tid + q*256; int r = flat >> 3, f4 = flat & 7;
      int k0 = kc + f4*4;
      float4 v = make_float4(0.f,0.f,0.f,0.f);
      if (k0 + 3 < NDW) v = *(const float4*)&Wwh[(size_t)r*NDW + k0];
      uint2 u; u.x = pack_bf16(v.x, v.y); u.y = pack_bf16(v.z, v.w);
      *(uint2*)&sB[r*16 + f4*2] = u;
    }
    __syncthreads();
    short8 a = *(const short8*)&sA[(wave*16 + (lane & 15))*16 + (lane >> 4)*4];
    #pragma unroll
    for (int ni = 0; ni < 8; ni++) {
      short8 b = *(const short8*)&sB[(ni*16 + (lane & 15))*16 + (lane >> 4)*4];
      acc[ni] = __builtin_amdgcn_mfma_f32_16x16x32_bf16(a, b, acc[ni], 0, 0, 0);
    }
  }
  int rbase = wave*16 + (lane >> 4)*4;
  #pragma unroll
  for (int ni = 0; ni < 8; ni++)
    #pragma unroll
    for (int reg = 0; reg < 4; reg++)
      wx[(rowbase + rbase + reg)*NH + ni*16 + (lane & 15)] = acc[ni][reg];
  float4 z = make_float4(0.f,0.f,0.f,0.f);
  #pragma unroll
  for (int q = 0; q < 8; q++) {
    int flat = tid + q*256; int r = flat >> 5, c = flat & 31;
    *(float4*)&hbuf[(rowbase + r)*NH + c*4] = z;
  }
}

// 4-node batched matvec, float2 lane mapping: lane owns output rows 2l,2l+1.
// One uint4 load per d4 serves both rows (adjacent in transposed table).
__device__ __forceinline__ void matvec4_T2(const uint2* __restrict__ wt,
    int lane, const float (*sv)[NH], float* o0, float* o1) {
  #pragma unroll
  for (int j = 0; j < 4; j++) { o0[j] = 0.f; o1[j] = 0.f; }
  #pragma unroll 4
  for (int d4 = 0; d4 < 32; d4++) {
    uint4 u = *(const uint4*)&wt[d4*128 + 2*lane];   // rows 2l (x,y), 2l+1 (z,w)
    float w00 = __uint_as_float(u.x << 16), w01 = __uint_as_float(u.x & 0xffff0000u);
    float w02 = __uint_as_float(u.y << 16), w03 = __uint_as_float(u.y & 0xffff0000u);
    float w10 = __uint_as_float(u.z << 16), w11 = __uint_as_float(u.z & 0xffff0000u);
    float w12 = __uint_as_float(u.w << 16), w13 = __uint_as_float(u.w & 0xffff0000u);
    #pragma unroll
    for (int j = 0; j < 4; j++) {
      float4 v = *(const float4*)&sv[j][d4*4];    // wave-uniform: LDS broadcast
      o0[j] += w00*v.x + w01*v.y + w02*v.z + w03*v.w;
      o1[j] += w10*v.x + w11*v.y + w12*v.z + w13*v.w;
    }
  }
}

// Phase k: nodes with height==k, bucketed by dep_type t=blockIdx&7:
//   h_i = tanh(hbuf_i + simple_i)  (simple_i at k==0) -> hbuf_i final
//   g_i = W_hr.h_i ; r = tanh(g_i + wx_parent); infl = W_rel[t].r -> atomicAdd hbuf[parent]
// j=4 (max wave parallelism), float2 lane mapping, coalesced bf16 weights; LDS 8KB.
__global__ __launch_bounds__(256, 4) void phase_kernel(
    const uint2* __restrict__ bwT, const float* __restrict__ bwh,
    const float* __restrict__ wx, const int* __restrict__ parent,
    const int* __restrict__ ib, float* __restrict__ hbuf, int k) {
  int t = blockIdx.x & 7, sub = blockIdx.x >> 3;     // 128 subs per type
  int bs = ib[OFF + k*NTYPE + t];
  int be = ib[OFF + k*NTYPE + t + 1];
  int nbat = (be - bs + 3) >> 2;
  if (sub*4 >= nbat) return;                         // uniform early-exit
  __shared__ __align__(16) float sh[4][4][NH];       // 8 KB
  int wave = threadIdx.x >> 6, lane = threadIdx.x & 63;
  int e0 = 2*lane;                                   // lane owns elements e0, e0+1
  const uint2* whr_t  = bwT;                         // mat 0
  const uint2* wrel_t = bwT + (size_t)(1 + t)*4096;  // mat 1+t
  float2 bv = *(const float2*)&bwh[e0];
  for (int b = sub*4 + wave; b < nbat; b += 128*4) {
    int base = bs + b*4;
    int cnt = be - base; if (cnt > 4) cnt = 4;
    int idxs[4], pidx[4];
    // pass 1: node indices
    #pragma unroll
    for (int j = 0; j < 4; j++) {
      int it = base + j; if (it >= be) it = be - 1;  // clamp tail (wave-uniform)
      idxs[j] = ib[NODE_LIST + it];
    }
    // pass 2: all row loads issued back-to-back (max loads in flight)
    float2 wxv[4], hb[4];
    #pragma unroll
    for (int j = 0; j < 4; j++)
      wxv[j] = *(const float2*)&wx[(size_t)idxs[j]*NH + e0];
    if (k > 0) {
      #pragma unroll
      for (int j = 0; j < 4; j++)
        hb[j] = *(const float2*)&hbuf[(size_t)idxs[j]*NH + e0];
    }
    #pragma unroll
    for (int j = 0; j < 4; j++) {
      int p = parent[idxs[j]];
      pidx[j] = (j < cnt && p >= 0) ? (idxs[j] & ~(NT-1)) + p : -1;
    }
    // prefetch parent wx rows early: latency hides under matvec1
    float2 pw[4];
    #pragma unroll
    for (int j = 0; j < 4; j++) {
      int p = pidx[j] >= 0 ? pidx[j] : idxs[j];
      pw[j] = *(const float2*)&wx[(size_t)p*NH + e0];
    }
    // finalize h, publish to LDS + hbuf
    #pragma unroll
    for (int j = 0; j < 4; j++) {
      float s0 = ftanh(wxv[j].x + bv.x);
      float s1 = ftanh(wxv[j].y + bv.y);
      float h0, h1;
      if (k == 0) { h0 = s0; h1 = s1; }
      else { h0 = ftanh(hb[j].x + s0); h1 = ftanh(hb[j].y + s1); }
      if (j < cnt)
        *(float2*)&hbuf[(size_t)idxs[j]*NH + e0] = make_float2(h0, h1);  // final h
      *(float2*)&sh[wave][j][e0] = make_float2(h0, h1);   // wave-synchronous LDS
    }
    float g0[4], g1[4];
    matvec4_T2(whr_t, lane, sh[wave], g0, g1);       // g = W_hr . h
    #pragma unroll
    for (int j = 0; j < 4; j++) {                    // r = tanh(g + wx_parent)
      float r0 = ftanh(g0[j] + pw[j].x);
      float r1 = ftanh(g1[j] + pw[j].y);
      *(float2*)&sh[wave][j][e0] = make_float2(r0, r1);
    }
    float o0[4], o1[4];
    matvec4_T2(wrel_t, lane, sh[wave], o0, o1);      // infl = W_rel[t] . r
    #pragma unroll
    for (int j = 0; j < 4; j++) if (pidx[j] >= 0) {
      atomicAdd(&hbuf[(size_t)pidx[j]*NH + e0],     o0[j]);
      atomicAdd(&hbuf[(size_t)pidx[j]*NH + e0 + 1], o1[j]);
    }
  }
}

extern "C" void kernel_launch(void* const* d_in, const int* in_sizes, int n_in,
                              void* d_out, int out_size, void* d_ws, size_t ws_size,
                              hipStream_t stream) {
  const float* token  = (const float*)d_in[0];
  const float* Wwh    = (const float*)d_in[1];
  const float* bwh    = (const float*)d_in[2];
  const float* Whr    = (const float*)d_in[3];
  const float* Wrel   = (const float*)d_in[4];
  const int*   parent = (const int*)d_in[5];
  const int*   dep    = (const int*)d_in[6];
  const int*   height = (const int*)d_in[7];

  float* hbuf = (float*)d_out;                          // seg-accumulator, then final h
  float* wx   = (float*)d_ws;                           // [NN,NH] f32, 16MB
  int*   ib   = (int*)((char*)d_ws + 16777216);         // bucket metadata + node list
  uint2* bwT  = (uint2*)((char*)d_ws + 16777216 + 1048576);  // 9*32KB bf16 weights

  wcvt_kernel<<<144, 256, 0, stream>>>(Whr, Wrel, bwT);
  count_kernel<<<CBLOCKS, 256, 0, stream>>>(dep, height, ib);
  scan_kernel<<<1, 128, 0, stream>>>(ib);
  scatter_kernel<<<CBLOCKS, 256, 0, stream>>>(dep, height, ib);
  wx_kernel<<<NN/64, 256, 0, stream>>>(token, Wwh, wx, hbuf);
  for (int k = 0; k < NLEVEL; k++)
    phase_kernel<<<PBLOCKS, 256, 0, stream>>>(bwT, bwh, wx, parent, ib, hbuf, k);
}